// Round 5
// baseline (96.701 us; speedup 1.0000x reference)
//
#include <hip/hip_runtime.h>

#define BB 2048          // batches
#define TT 4096          // timesteps
#define LN2 0.69314718055994530942f

// ---------------------------------------------------------------------------
// One-kernel CRF fold (round 5): 64-VGPR-tier version.
// gfx950 occupancy tiers are VGPR = 64/128/256 (waves/SIMD = 8/4/2). Round 3
// ran the 128-tier (full 16KB clause, 4 waves/SIMD, ~5.2 TB/s). This round
// targets the 64-tier: the 16-step clause is split into two half-clauses of
// 6 float4 each so the live-set (~24 Lf + 9 trans + 9 matrix + ~10 state)
// fits 64 VGPRs -> 8 waves/SIMD = 32 waves/CU. Two exposed-latency windows
// per chunk, but 2x the waves to cover them.
//   * tags (4x int4) issued first, packed to ONE reg (2 bits/tag) while the
//     6 half1 logit loads are still in flight (vmcnt(6) wait only).
//   * sched_barrier(0) pins the phase structure (no strip-mining).
//   * ordered shfl_down fold: lane i merges [i,i+m) x [i+m,i+2m); self is
//     always the LEFT operand -> no selects; lane 0 ends with the wave
//     product. Cross-wave fold via LDS; tid 0 writes per-batch nll.
// Failure signature if the tier bet is wrong: VGPR=64 + MB-scale WRITE_SIZE
// (spill) -> revert to round-3 envelope (launch_bounds(256,4), full clause).
// ---------------------------------------------------------------------------
__global__ __launch_bounds__(256, 8) void crf_pass1(
    const float* __restrict__ logits, const float* __restrict__ trans,
    const int* __restrict__ tags, float* __restrict__ ws)
{
    __shared__ float sTrans[9];
    __shared__ float sTrExp[9];
    __shared__ float sRec[3][12];      // records of waves 1..3
    const int tid = threadIdx.x;
    if (tid < 9) {
        float tv = trans[tid];
        sTrans[tid] = tv;
        sTrExp[tid] = __expf(tv);
    }
    __syncthreads();

    const int b = blockIdx.x;
    const int c = tid;                 // chunk index = thread index

    const int4*   tp = (const int4*)(tags + (size_t)b * TT + (size_t)c * 16);
    const float4* lp = (const float4*)(logits + ((size_t)b * TT + (size_t)c * 16) * 3);

    // ---- phase 0: issue tags + half1 logits ----
    int4 Tq[4];
#pragma unroll
    for (int i = 0; i < 4; ++i) Tq[i] = tp[i];
    float Lh1[24];
#pragma unroll
    for (int i = 0; i < 6; ++i) {
        float4 t = lp[i];
        Lh1[4*i+0] = t.x; Lh1[4*i+1] = t.y; Lh1[4*i+2] = t.z; Lh1[4*i+3] = t.w;
    }
    __builtin_amdgcn_sched_barrier(0);

    // pack 16 tags (values 0..2) into one reg; waits vmcnt(6) only
    unsigned pk = 0;
#pragma unroll
    for (int i = 0; i < 4; ++i) {
        pk |= ((unsigned)Tq[i].x << (8*i))     | ((unsigned)Tq[i].y << (8*i+2))
            | ((unsigned)Tq[i].z << (8*i+4))   | ((unsigned)Tq[i].w << (8*i+6));
    }

    float t00 = sTrExp[0], t01 = sTrExp[1], t02 = sTrExp[2];
    float t10 = sTrExp[3], t11 = sTrExp[4], t12 = sTrExp[5];
    float t20 = sTrExp[6], t21 = sTrExp[7], t22 = sTrExp[8];

    float a00 = 1.f, a01 = 0.f, a02 = 0.f;
    float a10 = 0.f, a11 = 1.f, a12 = 0.f;
    float a20 = 0.f, a21 = 0.f, a22 = 1.f;
    int   se = 0;
    float score = 0.f;
    unsigned long long acc = 0ull;     // 9 x 7-bit transition-pair counters
    int prev = 0;

#define MATSTEP(e0_, e1_, e2_) do {                                     \
    float x0 = __expf(e0_), x1 = __expf(e1_), x2 = __expf(e2_);         \
    float b0 = (a00*t00 + a01*t10 + a02*t20) * x0;                      \
    float b1 = (a00*t01 + a01*t11 + a02*t21) * x1;                      \
    float b2 = (a00*t02 + a01*t12 + a02*t22) * x2;                      \
    float b3 = (a10*t00 + a11*t10 + a12*t20) * x0;                      \
    float b4 = (a10*t01 + a11*t11 + a12*t21) * x1;                      \
    float b5 = (a10*t02 + a11*t12 + a12*t22) * x2;                      \
    float b6 = (a20*t00 + a21*t10 + a22*t20) * x0;                      \
    float b7 = (a20*t01 + a21*t11 + a22*t21) * x1;                      \
    float b8 = (a20*t02 + a21*t12 + a22*t22) * x2;                      \
    a00=b0; a01=b1; a02=b2; a10=b3; a11=b4; a12=b5; a20=b6; a21=b7; a22=b8; \
} while (0)

#define RENORM do {                                                     \
    float m_ = fmaxf(fmaxf(fmaxf(a00, a01), fmaxf(a02, a10)),           \
                     fmaxf(fmaxf(a11, a12), fmaxf(fmaxf(a20, a21), a22))); \
    int ef_ = (int)(__float_as_uint(m_) >> 23);                         \
    float scf_ = __uint_as_float((unsigned)(254 - ef_) << 23);          \
    se += ef_ - 127;                                                    \
    a00 *= scf_; a01 *= scf_; a02 *= scf_;                              \
    a10 *= scf_; a11 *= scf_; a12 *= scf_;                              \
    a20 *= scf_; a21 *= scf_; a22 *= scf_;                              \
} while (0)

#define DOSTEP(s_, e0_, e1_, e2_) do {                                  \
    int tg = (int)((pk >> (2*(s_))) & 3u);                              \
    if ((s_) == 0) {                                                    \
        if (c != 0) MATSTEP(e0_, e1_, e2_);                             \
    } else {                                                            \
        MATSTEP(e0_, e1_, e2_);                                         \
        acc += 1ull << (7 * (prev * 3 + tg));                           \
    }                                                                   \
    score += (tg == 0) ? (e0_) : ((tg == 1) ? (e1_) : (e2_));           \
    prev = tg;                                                          \
} while (0)

    // ---- phase 1: steps 0..7 from half1 ----
#pragma unroll
    for (int s = 0; s < 8; ++s) {
        DOSTEP(s, Lh1[3*s+0], Lh1[3*s+1], Lh1[3*s+2]);
    }
    RENORM;
    __builtin_amdgcn_sched_barrier(0);

    // ---- phase 2: issue half2 logits (reuses the dead Lh1 budget) ----
    float Lh2[24];
#pragma unroll
    for (int i = 0; i < 6; ++i) {
        float4 t = lp[6 + i];
        Lh2[4*i+0] = t.x; Lh2[4*i+1] = t.y; Lh2[4*i+2] = t.z; Lh2[4*i+3] = t.w;
    }
    __builtin_amdgcn_sched_barrier(0);

    // ---- phase 3: steps 8..15 from half2 ----
#pragma unroll
    for (int s = 8; s < 16; ++s) {
        DOSTEP(s, Lh2[3*(s-8)+0], Lh2[3*(s-8)+1], Lh2[3*(s-8)+2]);
    }
    RENORM;

    int firstTag = (int)(pk & 3u);

    // fold transition-pair counts into score (max count 15 < 127)
#pragma unroll
    for (int p = 0; p < 9; ++p)
        score += (float)((int)((acc >> (7 * p)) & 127ull)) * sTrans[p];

    // ---- ordered shfl_down fold of 64 chunk records (lane 0 ends valid) ----
#pragma unroll
    for (int m = 1; m < 64; m <<= 1) {
        float o00 = __shfl_down(a00, m, 64), o01 = __shfl_down(a01, m, 64), o02 = __shfl_down(a02, m, 64);
        float o10 = __shfl_down(a10, m, 64), o11 = __shfl_down(a11, m, 64), o12 = __shfl_down(a12, m, 64);
        float o20 = __shfl_down(a20, m, 64), o21 = __shfl_down(a21, m, 64), o22 = __shfl_down(a22, m, 64);
        int   ose = __shfl_down(se, m, 64);
        float osc = __shfl_down(score, m, 64);
        int   ofi = __shfl_down(firstTag, m, 64);   // right block's first tag
        int   opv = __shfl_down(prev, m, 64);       // right block's last tag

        // C = self(left) x other(right); no selects
        float c00 = a00*o00 + a01*o10 + a02*o20;
        float c01 = a00*o01 + a01*o11 + a02*o21;
        float c02 = a00*o02 + a01*o12 + a02*o22;
        float c10 = a10*o00 + a11*o10 + a12*o20;
        float c11 = a10*o01 + a11*o11 + a12*o21;
        float c12 = a10*o02 + a11*o12 + a12*o22;
        float c20 = a20*o00 + a21*o10 + a22*o20;
        float c21 = a20*o01 + a21*o11 + a22*o21;
        float c22 = a20*o02 + a21*o12 + a22*o22;

        score = score + osc + sTrans[prev * 3 + ofi];  // seam transition
        prev = opv;
        se += ose;

        a00=c00; a01=c01; a02=c02; a10=c10; a11=c11; a12=c12; a20=c20; a21=c21; a22=c22;
        RENORM;
    }

    // ---- cross-wave fold (waves are time-ordered) ----
    const int lane = tid & 63;
    const int wid  = tid >> 6;
    if (lane == 0 && wid > 0) {
        sRec[wid-1][0] = a00; sRec[wid-1][1] = a01; sRec[wid-1][2] = a02;
        sRec[wid-1][3] = a10; sRec[wid-1][4] = a11; sRec[wid-1][5] = a12;
        sRec[wid-1][6] = a20; sRec[wid-1][7] = a21; sRec[wid-1][8] = a22;
        sRec[wid-1][9]  = __int_as_float(se);
        sRec[wid-1][10] = score;
        sRec[wid-1][11] = __int_as_float(firstTag | (prev << 8));
    }
    __syncthreads();
    if (tid == 0) {
#pragma unroll
        for (int k = 0; k < 3; ++k) {
            float m00 = sRec[k][0], m01 = sRec[k][1], m02 = sRec[k][2];
            float m10 = sRec[k][3], m11 = sRec[k][4], m12 = sRec[k][5];
            float m20 = sRec[k][6], m21 = sRec[k][7], m22 = sRec[k][8];
            int   shm = __float_as_int(sRec[k][9]);
            float scm = sRec[k][10];
            int   pkm = __float_as_int(sRec[k][11]);

            float c00 = a00*m00 + a01*m10 + a02*m20;
            float c01 = a00*m01 + a01*m11 + a02*m21;
            float c02 = a00*m02 + a01*m12 + a02*m22;
            float c10 = a10*m00 + a11*m10 + a12*m20;
            float c11 = a10*m01 + a11*m11 + a12*m21;
            float c12 = a10*m02 + a11*m12 + a12*m22;
            float c20 = a20*m00 + a21*m10 + a22*m20;
            float c21 = a20*m01 + a21*m11 + a22*m21;
            float c22 = a20*m02 + a21*m12 + a22*m22;

            score += scm + sTrans[prev * 3 + (pkm & 255)];
            prev = pkm >> 8;
            se += shm;
            a00=c00; a01=c01; a02=c02; a10=c10; a11=c11; a12=c12; a20=c20; a21=c21; a22=c22;
            RENORM;
        }
        // alpha0 re-read (L1-hit: same line thread 0's clause already fetched)
        const float* lb = logits + (size_t)b * TT * 3;
        float v0 = __expf(lb[0]);
        float v1 = __expf(lb[1]);
        float v2 = __expf(lb[2]);
        // alpha_T = v . P  (row-vector times total product), value * 2^se
        float n0 = v0*a00 + v1*a10 + v2*a20;
        float n1 = v0*a01 + v1*a11 + v2*a21;
        float n2 = v0*a02 + v1*a12 + v2*a22;
        float logz = logf(n0 + n1 + n2) + (float)se * LN2;
        ws[b] = logz - score;          // per-batch nll
    }

#undef MATSTEP
#undef RENORM
#undef DOSTEP
}

// ---------------------------------------------------------------------------
// Final reduction: one block sums the 2048 per-batch nll values.
// ---------------------------------------------------------------------------
__global__ __launch_bounds__(256) void crf_reduce(
    const float* __restrict__ ws, float* __restrict__ out)
{
    int tid = threadIdx.x;
    float s = 0.f;
#pragma unroll
    for (int k = 0; k < BB / 256; ++k) s += ws[k * 256 + tid];
    for (int off = 32; off > 0; off >>= 1) s += __shfl_down(s, off, 64);
    __shared__ float sP[4];
    if ((tid & 63) == 0) sP[tid >> 6] = s;
    __syncthreads();
    if (tid == 0) out[0] = sP[0] + sP[1] + sP[2] + sP[3];
}

extern "C" void kernel_launch(void* const* d_in, const int* in_sizes, int n_in,
                              void* d_out, int out_size, void* d_ws, size_t ws_size,
                              hipStream_t stream) {
    const float* logits = (const float*)d_in[0];
    const float* trans  = (const float*)d_in[1];
    const int*   tags   = (const int*)d_in[2];
    float* out = (float*)d_out;
    float* ws  = (float*)d_ws;

    crf_pass1<<<dim3(BB), dim3(256), 0, stream>>>(logits, trans, tags, ws);
    crf_reduce<<<dim3(1), dim3(256), 0, stream>>>(ws, out);
}

// Round 6
// 49.070 us; speedup vs baseline: 1.9707x; 1.9707x over previous
//
#include <hip/hip_runtime.h>

#define BB 2048          // batches
#define TT 4096          // timesteps
#define LN2 0.69314718055994530942f
#define ROWS 2           // batch rows per block (1024 blocks -> single generation)

// ---------------------------------------------------------------------------
// One-kernel CRF fold (round 6) — back to the proven 128-VGPR tier (256,4).
// New vs round 3:
//   * ROWS=2: each block folds TWO batch rows. Grid = 1024 blocks = 4/CU all
//     resident at once -> NO generation boundaries (R3 had 8 per CU, each
//     exposing ~900cy of synchronized load latency).
//   * Software pipeline across rows (T14): row r+1's full 16-load clause is
//     issued AFTER row r's last MATSTEP (Lf dead) and BEFORE row r's fold;
//     the ~1000cy fold+tail hides the ~900cy load latency.
//   * thread 0 stashes v = exp(Lf[0..2]) per row (alpha0) — no tail re-read.
//   * fold shuffles pack firstTag|prev into one word (3 aux shfls/round).
// Envelope lesson (R2/R4/R5): gfx950 occupancy tiers are VGPR=64/128/256;
// requesting waves the live-set can't fit makes hipcc allocate BELOW the tier
// and spill (VGPR=32/48 + MB-scale WRITE_SIZE). Stay at (256,4).
// ---------------------------------------------------------------------------
__global__ __launch_bounds__(256, 4) void crf_pass1(
    const float* __restrict__ logits, const float* __restrict__ trans,
    const int* __restrict__ tags, float* __restrict__ ws)
{
    __shared__ float sTrans[9];
    __shared__ float sTrExp[9];
    __shared__ float sRec[3][12];      // records of waves 1..3
    const int tid = threadIdx.x;
    if (tid < 9) {
        float tv = trans[tid];
        sTrans[tid] = tv;
        sTrExp[tid] = __expf(tv);
    }
    __syncthreads();

    const int c  = tid;                // chunk index within a row
    const int b0 = blockIdx.x * ROWS;

    // ---- prologue: issue row-0 clause (tags first, then logits) ----
    int4  Tq[4];
    float Lf[48];
    {
        const int4*   tp = (const int4*)(tags + (size_t)b0 * TT + (size_t)c * 16);
        const float4* lp = (const float4*)(logits + ((size_t)b0 * TT + (size_t)c * 16) * 3);
#pragma unroll
        for (int i = 0; i < 4; ++i) Tq[i] = tp[i];
#pragma unroll
        for (int i = 0; i < 12; ++i) {
            float4 t = lp[i];
            Lf[4*i+0] = t.x; Lf[4*i+1] = t.y; Lf[4*i+2] = t.z; Lf[4*i+3] = t.w;
        }
    }
    __builtin_amdgcn_sched_barrier(0);

    const float t00 = sTrExp[0], t01 = sTrExp[1], t02 = sTrExp[2];
    const float t10 = sTrExp[3], t11 = sTrExp[4], t12 = sTrExp[5];
    const float t20 = sTrExp[6], t21 = sTrExp[7], t22 = sTrExp[8];

#define MATSTEP(e0_, e1_, e2_) do {                                     \
    float x0 = __expf(e0_), x1 = __expf(e1_), x2 = __expf(e2_);         \
    float b0_ = (a00*t00 + a01*t10 + a02*t20) * x0;                     \
    float b1_ = (a00*t01 + a01*t11 + a02*t21) * x1;                     \
    float b2_ = (a00*t02 + a01*t12 + a02*t22) * x2;                     \
    float b3_ = (a10*t00 + a11*t10 + a12*t20) * x0;                     \
    float b4_ = (a10*t01 + a11*t11 + a12*t21) * x1;                     \
    float b5_ = (a10*t02 + a11*t12 + a12*t22) * x2;                     \
    float b6_ = (a20*t00 + a21*t10 + a22*t20) * x0;                     \
    float b7_ = (a20*t01 + a21*t11 + a22*t21) * x1;                     \
    float b8_ = (a20*t02 + a21*t12 + a22*t22) * x2;                     \
    a00=b0_; a01=b1_; a02=b2_; a10=b3_; a11=b4_; a12=b5_; a20=b6_; a21=b7_; a22=b8_; \
} while (0)

#define RENORM do {                                                     \
    float m_ = fmaxf(fmaxf(fmaxf(a00, a01), fmaxf(a02, a10)),           \
                     fmaxf(fmaxf(a11, a12), fmaxf(fmaxf(a20, a21), a22))); \
    int ef_ = (int)(__float_as_uint(m_) >> 23);                         \
    float scf_ = __uint_as_float((unsigned)(254 - ef_) << 23);          \
    se += ef_ - 127;                                                    \
    a00 *= scf_; a01 *= scf_; a02 *= scf_;                              \
    a10 *= scf_; a11 *= scf_; a12 *= scf_;                              \
    a20 *= scf_; a21 *= scf_; a22 *= scf_;                              \
} while (0)

#pragma unroll
    for (int r = 0; r < ROWS; ++r) {
        const int b = b0 + r;

        // pack 16 tags (0..2) into one reg (Tq loaded long ago -> no stall)
        unsigned pk = 0;
#pragma unroll
        for (int i = 0; i < 4; ++i) {
            pk |= ((unsigned)Tq[i].x << (8*i))   | ((unsigned)Tq[i].y << (8*i+2))
                | ((unsigned)Tq[i].z << (8*i+4)) | ((unsigned)Tq[i].w << (8*i+6));
        }
        const int firstTag = (int)(pk & 3u);

        float a00 = 1.f, a01 = 0.f, a02 = 0.f;
        float a10 = 0.f, a11 = 1.f, a12 = 0.f;
        float a20 = 0.f, a21 = 0.f, a22 = 1.f;
        int   se = 0;
        float score = 0.f;
        unsigned long long acc = 0ull;   // 9 x 7-bit transition-pair counters
        int prev = 0;
        float v0 = 0.f, v1 = 0.f, v2 = 0.f;   // alpha0 (thread 0 of the row)

        // ---- 16 steps ----
#pragma unroll
        for (int s = 0; s < 16; ++s) {
            float e0 = Lf[3*s+0], e1 = Lf[3*s+1], e2 = Lf[3*s+2];
            int tg = (int)((pk >> (2*s)) & 3u);
            if (s == 0) {
                if (c == 0) {            // t=0 of this row: alpha0
                    v0 = __expf(e0); v1 = __expf(e1); v2 = __expf(e2);
                } else {
                    MATSTEP(e0, e1, e2);
                }
            } else {
                MATSTEP(e0, e1, e2);
                acc += 1ull << (7 * (prev * 3 + tg));
            }
            score += (tg == 0) ? e0 : ((tg == 1) ? e1 : e2);
            prev = tg;
            if ((s & 7) == 7) RENORM;
        }

        // ---- issue next row's clause NOW (Lf/Tq dead) — fold hides latency
        if (r + 1 < ROWS) {
            const int4*   tp2 = (const int4*)(tags + (size_t)(b + 1) * TT + (size_t)c * 16);
            const float4* lp2 = (const float4*)(logits + ((size_t)(b + 1) * TT + (size_t)c * 16) * 3);
#pragma unroll
            for (int i = 0; i < 4; ++i) Tq[i] = tp2[i];
#pragma unroll
            for (int i = 0; i < 12; ++i) {
                float4 t = lp2[i];
                Lf[4*i+0] = t.x; Lf[4*i+1] = t.y; Lf[4*i+2] = t.z; Lf[4*i+3] = t.w;
            }
        }
        __builtin_amdgcn_sched_barrier(0);

        // fold transition-pair counts into score (max count 15 < 127)
#pragma unroll
        for (int p = 0; p < 9; ++p)
            score += (float)((int)((acc >> (7 * p)) & 127ull)) * sTrans[p];

        // ---- ordered shfl_down fold of 64 chunk records (lane 0 ends valid)
        int fT = firstTag;               // mutable copy for the fold
        int fp = fT | (prev << 8);       // packed firstTag|last for shuffling
#pragma unroll
        for (int m = 1; m < 64; m <<= 1) {
            float o00 = __shfl_down(a00, m, 64), o01 = __shfl_down(a01, m, 64), o02 = __shfl_down(a02, m, 64);
            float o10 = __shfl_down(a10, m, 64), o11 = __shfl_down(a11, m, 64), o12 = __shfl_down(a12, m, 64);
            float o20 = __shfl_down(a20, m, 64), o21 = __shfl_down(a21, m, 64), o22 = __shfl_down(a22, m, 64);
            int   ose = __shfl_down(se, m, 64);
            float osc = __shfl_down(score, m, 64);
            int   ofp = __shfl_down(fp, m, 64);   // right block's firstTag|last

            // C = self(left) x other(right); no selects
            float c00 = a00*o00 + a01*o10 + a02*o20;
            float c01 = a00*o01 + a01*o11 + a02*o21;
            float c02 = a00*o02 + a01*o12 + a02*o22;
            float c10 = a10*o00 + a11*o10 + a12*o20;
            float c11 = a10*o01 + a11*o11 + a12*o21;
            float c12 = a10*o02 + a11*o12 + a12*o22;
            float c20 = a20*o00 + a21*o10 + a22*o20;
            float c21 = a20*o01 + a21*o11 + a22*o21;
            float c22 = a20*o02 + a21*o12 + a22*o22;

            score = score + osc + sTrans[(fp >> 8) * 3 + (ofp & 255)]; // seam
            fp = (fp & 255) | (ofp & ~255);     // keep left first, take right last
            se += ose;

            a00=c00; a01=c01; a02=c02; a10=c10; a11=c11; a12=c12; a20=c20; a21=c21; a22=c22;
            RENORM;
        }
        prev = fp >> 8;
        fT   = fp & 255;

        // ---- cross-wave fold (waves are time-ordered) ----
        const int lane = tid & 63;
        const int wid  = tid >> 6;
        __syncthreads();                 // sRec safe to overwrite (prev row done)
        if (lane == 0 && wid > 0) {
            sRec[wid-1][0] = a00; sRec[wid-1][1] = a01; sRec[wid-1][2] = a02;
            sRec[wid-1][3] = a10; sRec[wid-1][4] = a11; sRec[wid-1][5] = a12;
            sRec[wid-1][6] = a20; sRec[wid-1][7] = a21; sRec[wid-1][8] = a22;
            sRec[wid-1][9]  = __int_as_float(se);
            sRec[wid-1][10] = score;
            sRec[wid-1][11] = __int_as_float(fT | (prev << 8));
        }
        __syncthreads();
        if (tid == 0) {
#pragma unroll
            for (int k = 0; k < 3; ++k) {
                float m00 = sRec[k][0], m01 = sRec[k][1], m02 = sRec[k][2];
                float m10 = sRec[k][3], m11 = sRec[k][4], m12 = sRec[k][5];
                float m20 = sRec[k][6], m21 = sRec[k][7], m22 = sRec[k][8];
                int   shm = __float_as_int(sRec[k][9]);
                float scm = sRec[k][10];
                int   pkm = __float_as_int(sRec[k][11]);

                float c00 = a00*m00 + a01*m10 + a02*m20;
                float c01 = a00*m01 + a01*m11 + a02*m21;
                float c02 = a00*m02 + a01*m12 + a02*m22;
                float c10 = a10*m00 + a11*m10 + a12*m20;
                float c11 = a10*m01 + a11*m11 + a12*m21;
                float c12 = a10*m02 + a11*m12 + a12*m22;
                float c20 = a20*m00 + a21*m10 + a22*m20;
                float c21 = a20*m01 + a21*m11 + a22*m21;
                float c22 = a20*m02 + a21*m12 + a22*m22;

                score += scm + sTrans[prev * 3 + (pkm & 255)];
                prev = pkm >> 8;
                se += shm;
                a00=c00; a01=c01; a02=c02; a10=c10; a11=c11; a12=c12; a20=c20; a21=c21; a22=c22;
                RENORM;
            }
            // alpha_T = v . P (row-vector times total product), value * 2^se
            float n0 = v0*a00 + v1*a10 + v2*a20;
            float n1 = v0*a01 + v1*a11 + v2*a21;
            float n2 = v0*a02 + v1*a12 + v2*a22;
            float logz = logf(n0 + n1 + n2) + (float)se * LN2;
            ws[b] = logz - score;        // per-batch nll
        }
    }

#undef MATSTEP
#undef RENORM
}

// ---------------------------------------------------------------------------
// Final reduction: one block sums the 2048 per-batch nll values.
// ---------------------------------------------------------------------------
__global__ __launch_bounds__(256) void crf_reduce(
    const float* __restrict__ ws, float* __restrict__ out)
{
    int tid = threadIdx.x;
    float s = 0.f;
#pragma unroll
    for (int k = 0; k < BB / 256; ++k) s += ws[k * 256 + tid];
    for (int off = 32; off > 0; off >>= 1) s += __shfl_down(s, off, 64);
    __shared__ float sP[4];
    if ((tid & 63) == 0) sP[tid >> 6] = s;
    __syncthreads();
    if (tid == 0) out[0] = sP[0] + sP[1] + sP[2] + sP[3];
}

extern "C" void kernel_launch(void* const* d_in, const int* in_sizes, int n_in,
                              void* d_out, int out_size, void* d_ws, size_t ws_size,
                              hipStream_t stream) {
    const float* logits = (const float*)d_in[0];
    const float* trans  = (const float*)d_in[1];
    const int*   tags   = (const int*)d_in[2];
    float* out = (float*)d_out;
    float* ws  = (float*)d_ws;

    crf_pass1<<<dim3(BB / ROWS), dim3(256), 0, stream>>>(logits, trans, tags, ws);
    crf_reduce<<<dim3(1), dim3(256), 0, stream>>>(ws, out);
}